// Round 7
// baseline (232.990 us; speedup 1.0000x reference)
//
#include <hip/hip_runtime.h>
#include <hip/hip_bf16.h>

constexpr int Sdim = 256;
constexpr int Cdim = 128;
constexpr int CRdim = 32;
constexpr int Bdim = 2;
constexpr int SS = Sdim * Sdim;      // 65536
constexpr int NPOS = Bdim * SS;      // 131072

typedef __attribute__((ext_vector_type(8))) short short8v;
typedef __attribute__((ext_vector_type(8))) unsigned short ushort8v;
typedef __attribute__((ext_vector_type(4))) float float4v;

__device__ __forceinline__ float bf2f(unsigned short v) {
    union { unsigned u; float f; } t; t.u = ((unsigned)v) << 16; return t.f;
}
__device__ __forceinline__ unsigned short f2bf(float f) {
    unsigned u = __float_as_uint(f);
    return (unsigned short)((u + 0x7fffu + ((u >> 16) & 1u)) >> 16);
}
__device__ __forceinline__ unsigned lds_addr_of(const void* p) {
    return (unsigned)(uintptr_t)(__attribute__((address_space(3))) const void*)p;
}

// ---------------- K0: weight prep ----------------
// All MFMA A-fragments use pi(g,i) = g*4+i (i<4) else 16+g*4+(i-4), matching
// the B-side ds_read_b64_tr_b16 order (verified by round-5 k_merge_mfma).
__global__ void k_prep(const float* __restrict__ w_reduce,
                       const float* __restrict__ w_u, const float* __restrict__ w_lam,
                       const float* __restrict__ w_w,
                       const float* __restrict__ b_red, const float* __restrict__ b_u,
                       const float* __restrict__ b_lam, const float* __restrict__ b_w,
                       const float* __restrict__ w_merge,
                       unsigned short* __restrict__ wm_frag,
                       unsigned short* __restrict__ wredA,
                       unsigned short* __restrict__ wuA, unsigned short* __restrict__ wlamA,
                       float* __restrict__ biasFrag,
                       float* __restrict__ buFrag, float* __restrict__ blamFrag)
{
    int t = blockIdx.x * 256 + threadIdx.x;   // 0..16383
    #pragma unroll
    for (int rep = 0; rep < 2; ++rep) {
        int f = t + rep * 16384;              // 0..32767
        int fi = f & 7, fl = (f >> 3) & 63, mt = (f >> 9) & 7, ks = (f >> 12) & 7;
        int fg = fl >> 4;
        int fk = (fi < 4) ? (fg * 4 + fi) : (16 + fg * 4 + (fi - 4));
        int cc = ks * 32 + fk;
        int co = mt * 16 + (fl & 15);
        float v;
        if (cc < 128) v = w_merge[co * 512 + cc]       + w_merge[co * 512 + cc + 128];
        else          v = w_merge[co * 512 + cc + 128] + w_merge[co * 512 + cc + 256];
        wm_frag[f] = f2bf(v);
    }

    int i = t & 7, lane = (t >> 3) & 63;
    int g = lane >> 4;
    int kk = (i < 4) ? (g * 4 + i) : (16 + g * 4 + (i - 4));

    if (t < 6144) {   // red/pre GEMM A-frags: [ks(4)][mt(3)][lane][i], K=128
        int q = t >> 9, mt = q % 3, ks = q / 3;
        int k = ks * 32 + kk;
        int row = mt * 16 + (lane & 15);
        float v = 0.f;
        if (row < 32) v = w_reduce[row * 128 + k];
        else if (row < 35) {
            int r = row - 32;
            for (int cr = 0; cr < 32; ++cr) v += w_w[r * 32 + cr] * w_reduce[cr * 128 + k];
        }
        wredA[t] = f2bf(v);
    }
    if (t < 4096) {   // u/lam GEMM A-frags: [mt(8)][lane][i], K=32 (kk = cr)
        int mt = t >> 9;
        int co = mt * 16 + (lane & 15);
        wuA[t]   = f2bf(w_u[co * 32 + kk]);
        wlamA[t] = f2bf(w_lam[co * 32 + kk]);
    }
    if (t < 768) {    // bias in D-frag layout for red/pre rows
        int r = t & 3, ln = (t >> 2) & 63, mt = t >> 8;
        int row = mt * 16 + (ln >> 4) * 4 + r;
        float v = 0.f;
        if (row < 32) v = b_red[row];
        else if (row < 35) {
            int rr = row - 32;
            v = b_w[rr];
            for (int cr = 0; cr < 32; ++cr) v += w_w[rr * 32 + cr] * b_red[cr];
        }
        biasFrag[t] = v;
    }
    if (t < 2048) {   // u/lam bias in D-frag layout
        int r = t & 3, ln = (t >> 2) & 63, mt = t >> 8;
        int co = mt * 16 + (ln >> 4) * 4 + r;
        buFrag[t]   = b_u[co];
        blamFrag[t] = b_lam[co];
    }
}

// ---------------- K1: fused front end via MFMA (verified round 6) ----------------
__global__ __launch_bounds__(256, 4) void k_front(
    const float* __restrict__ x,
    const unsigned short* __restrict__ wredA, const float* __restrict__ biasFrag,
    const unsigned short* __restrict__ wuA, const unsigned short* __restrict__ wlamA,
    const float* __restrict__ buFrag, const float* __restrict__ blamFrag,
    unsigned short* __restrict__ u_o, unsigned short* __restrict__ v_o,
    float* __restrict__ Gv, float* __restrict__ Gh)
{
    __shared__ unsigned short lds[20480];   // 32KB X-tile + 8KB red-tile
    const int t   = threadIdx.x;
    const int p0  = blockIdx.x * 128;
    const int b   = p0 >> 16;
    const int hw0 = p0 & (SS - 1);

    {
        const int w0 = (t & 15) * 8;
        #pragma unroll
        for (int pass = 0; pass < 8; ++pass) {
            int c = (t >> 4) + pass * 16;
            const float* src = x + (((size_t)(b * Cdim + c)) << 16) + hw0 + w0;
            float4 xa = *reinterpret_cast<const float4*>(src);
            float4 xb = *reinterpret_cast<const float4*>(src + 4);
            ushort8v val;
            val[0] = f2bf(xa.x); val[1] = f2bf(xa.y); val[2] = f2bf(xa.z); val[3] = f2bf(xa.w);
            val[4] = f2bf(xb.x); val[5] = f2bf(xb.y); val[6] = f2bf(xb.z); val[7] = f2bf(xb.w);
            int off = ((w0 >> 4) << 11) + ((c >> 2) << 6) + ((c & 3) << 4) + (w0 & 15);
            *reinterpret_cast<ushort8v*>(&lds[off]) = val;
        }
    }
    __syncthreads();

    const int lane = t & 63;
    const int wave = t >> 6;
    const int g    = lane >> 4;

    const unsigned vx = lds_addr_of(lds)
        + (unsigned)((wave << 13) + (g << 7) + ((lane & 15) << 3));

    float4v redD[3][2];
    #pragma unroll
    for (int mt = 0; mt < 3; ++mt) {
        redD[mt][0] = (float4v){0.f, 0.f, 0.f, 0.f};
        redD[mt][1] = (float4v){0.f, 0.f, 0.f, 0.f};
    }
    const short8v* wfr = reinterpret_cast<const short8v*>(wredA);
    #pragma unroll
    for (int ks = 0; ks < 4; ++ks) {
        short8v a0 = wfr[(ks * 3 + 0) * 64 + lane];
        short8v a1 = wfr[(ks * 3 + 1) * 64 + lane];
        short8v a2 = wfr[(ks * 3 + 2) * 64 + lane];
        unsigned ka = vx + (unsigned)(ks << 10);
        unsigned long long q00, q01, q10, q11;
        asm volatile(
            "ds_read_b64_tr_b16 %0, %4 offset:0\n\t"
            "ds_read_b64_tr_b16 %1, %4 offset:512\n\t"
            "ds_read_b64_tr_b16 %2, %4 offset:4096\n\t"
            "ds_read_b64_tr_b16 %3, %4 offset:4608\n\t"
            "s_waitcnt lgkmcnt(0)"
            : "=&v"(q00), "=&v"(q01), "=&v"(q10), "=&v"(q11)
            : "v"(ka));
        __builtin_amdgcn_sched_barrier(0);
        union { unsigned long long u[2]; short8v v; } f0, f1;
        f0.u[0] = q00; f0.u[1] = q01;
        f1.u[0] = q10; f1.u[1] = q11;
        short8v bn0 = f0.v, bn1 = f1.v;
        redD[0][0] = __builtin_amdgcn_mfma_f32_16x16x32_bf16(a0, bn0, redD[0][0], 0, 0, 0);
        redD[0][1] = __builtin_amdgcn_mfma_f32_16x16x32_bf16(a0, bn1, redD[0][1], 0, 0, 0);
        redD[1][0] = __builtin_amdgcn_mfma_f32_16x16x32_bf16(a1, bn0, redD[1][0], 0, 0, 0);
        redD[1][1] = __builtin_amdgcn_mfma_f32_16x16x32_bf16(a1, bn1, redD[1][1], 0, 0, 0);
        redD[2][0] = __builtin_amdgcn_mfma_f32_16x16x32_bf16(a2, bn0, redD[2][0], 0, 0, 0);
        redD[2][1] = __builtin_amdgcn_mfma_f32_16x16x32_bf16(a2, bn1, redD[2][1], 0, 0, 0);
    }

    {
        float4 bp = *reinterpret_cast<const float4*>(biasFrag + ((2 * 64 + lane) << 2));
        if (lane < 16) {
            #pragma unroll
            for (int nt = 0; nt < 2; ++nt) {
                float pr0 = redD[2][nt][0] + bp.x;
                float pr1 = redD[2][nt][1] + bp.y;
                float pr2 = redD[2][nt][2] + bp.z;
                float s0 = 1.f / (1.f + expf(-pr0));
                float s1 = 1.f / (1.f + expf(-pr1));
                float s2 = 1.f / (1.f + expf(-pr2));
                float inv = 1.f / fmaxf(s0 + s1 + s2, 1e-6f);
                int hw = hw0 + wave * 32 + nt * 16 + lane;
                int hh = hw >> 8, wp = hw & 255;
                float ghv = (s1 + (hh >= 1 ? s0 : 0.f) + (hh <= Sdim - 2 ? s2 : 0.f)) * inv;
                float gvv = (s1 + (wp >= 1 ? s0 : 0.f) + (wp <= Sdim - 2 ? s2 : 0.f)) * inv;
                Gh[(b << 16) + hw] = ghv;
                Gv[(b << 16) + (wp << 8) + hh] = gvv;
            }
        }
    }

    #pragma unroll
    for (int mt = 0; mt < 2; ++mt) {
        float4 bb = *reinterpret_cast<const float4*>(biasFrag + ((mt * 64 + lane) << 2));
        #pragma unroll
        for (int nt = 0; nt < 2; ++nt) {
            int pp = wave * 32 + nt * 16 + (lane & 15);
            #pragma unroll
            for (int r = 0; r < 4; ++r) {
                int cr = mt * 16 + g * 4 + r;
                float bval = (r == 0 ? bb.x : r == 1 ? bb.y : r == 2 ? bb.z : bb.w);
                int off = 16384 + ((pp >> 4) << 9) + ((cr >> 2) << 6) + ((cr & 3) << 4) + (pp & 15);
                lds[off] = f2bf(redD[mt][nt][r] + bval);
            }
        }
    }
    __syncthreads();

    const unsigned vr = lds_addr_of(lds) + 32768u
        + (unsigned)((wave << 11) + (g << 7) + ((lane & 15) << 3));
    unsigned long long q00, q01, q10, q11;
    asm volatile(
        "ds_read_b64_tr_b16 %0, %4 offset:0\n\t"
        "ds_read_b64_tr_b16 %1, %4 offset:512\n\t"
        "ds_read_b64_tr_b16 %2, %4 offset:1024\n\t"
        "ds_read_b64_tr_b16 %3, %4 offset:1536\n\t"
        "s_waitcnt lgkmcnt(0)"
        : "=&v"(q00), "=&v"(q01), "=&v"(q10), "=&v"(q11)
        : "v"(vr));
    __builtin_amdgcn_sched_barrier(0);
    union { unsigned long long u[2]; short8v v; } fb0, fb1;
    fb0.u[0] = q00; fb0.u[1] = q01;
    fb1.u[0] = q10; fb1.u[1] = q11;
    short8v bn0 = fb0.v, bn1 = fb1.v;

    const short8v* wfu = reinterpret_cast<const short8v*>(wuA);
    const short8v* wfl = reinterpret_cast<const short8v*>(wlamA);
    const float4v zz = (float4v){0.f, 0.f, 0.f, 0.f};
    #pragma unroll
    for (int mt = 0; mt < 8; ++mt) {
        short8v au = wfu[(mt << 6) + lane];
        short8v al = wfl[(mt << 6) + lane];
        float4v u0 = __builtin_amdgcn_mfma_f32_16x16x32_bf16(au, bn0, zz, 0, 0, 0);
        float4v u1 = __builtin_amdgcn_mfma_f32_16x16x32_bf16(au, bn1, zz, 0, 0, 0);
        float4v l0 = __builtin_amdgcn_mfma_f32_16x16x32_bf16(al, bn0, zz, 0, 0, 0);
        float4v l1 = __builtin_amdgcn_mfma_f32_16x16x32_bf16(al, bn1, zz, 0, 0, 0);
        float4 bu = *reinterpret_cast<const float4*>(buFrag + ((mt * 64 + lane) << 2));
        float4 bl = *reinterpret_cast<const float4*>(blamFrag + ((mt * 64 + lane) << 2));
        #pragma unroll
        for (int nt = 0; nt < 2; ++nt) {
            float4v uu = nt ? u1 : u0;
            float4v ll = nt ? l1 : l0;
            int pp = wave * 32 + nt * 16 + (lane & 15);
            #pragma unroll
            for (int r = 0; r < 4; ++r) {
                int co = mt * 16 + g * 4 + r;
                int xoff = ((pp >> 4) << 11) + ((co >> 2) << 6) + ((co & 3) << 4) + (pp & 15);
                float xv = bf2f(lds[xoff]);
                float bur = (r == 0 ? bu.x : r == 1 ? bu.y : r == 2 ? bu.z : bu.w);
                float blr = (r == 0 ? bl.x : r == 1 ? bl.y : r == 2 ? bl.z : bl.w);
                size_t gidx = (((size_t)(b * Cdim + co)) << 16) + (size_t)(hw0 + pp);
                u_o[gidx] = f2bf(uu[r] + bur);
                v_o[gidx] = f2bf((ll[r] + blr) * xv);
            }
        }
    }
}

// ---------------- K2: chunked scans (scan-then-propagate) ----------------
// Block = 1024 threads = (chunk q = tid>>8 in 0..3, column j = tid&255).
// Phase 1: local 64-step scan -> (L, P) only.  Phase 2: LDS carry combine
// (q is wave-uniform -> no divergence).  Phase 3: rescan with carry, * u.
// Raises grid from 2048 to 8192 waves (device-full) and cuts the serial
// chain 256 -> 64; recompute doubles VALU work (was 10% busy) and rereads
// v from L2/L3.
__global__ __launch_bounds__(1024, 2) void k_scan_chunked(
    const unsigned short* __restrict__ u, const unsigned short* __restrict__ v,
    const float* __restrict__ Gv, const float* __restrict__ Gh,
    unsigned short* __restrict__ ov, unsigned short* __restrict__ oh)
{
    __shared__ float Ls[4][256];
    __shared__ float Ps[4][256];

    const int id = blockIdx.x;
    const int j  = threadIdx.x & 255;
    const int q  = threadIdx.x >> 8;      // wave-uniform
    const int i0 = q * 64;

    if (id < Bdim * Cdim) {
        // vertical: lanes = consecutive j -> all accesses coalesced
        int bc = id, b = bc >> 7;
        size_t base = (size_t)bc * SS + j;
        const float* Gb = Gv + (b << 16) + j;

        float L = 0.f, P = 1.f;
        #pragma unroll 8
        for (int t = 0; t < 64; ++t) {
            int i = i0 + t;
            float g = Gb[i << 8];
            L = fmaf(L, g, bf2f(v[base + ((size_t)i << 8)]));
            P *= g;
        }
        Ls[q][j] = L; Ps[q][j] = P;
        __syncthreads();
        float C = 0.f;
        for (int r = 0; r < q; ++r) C = Ls[r][j] + C * Ps[r][j];

        float h = C;
        #pragma unroll 4
        for (int t = 0; t < 64; ++t) {
            int i = i0 + t;
            size_t idx = base + ((size_t)i << 8);
            float g = Gb[i << 8];
            h = fmaf(h, g, bf2f(v[idx]));
            ov[idx] = f2bf(h * bf2f(u[idx]));
        }
    } else {
        // horizontal: per-thread contiguous ushort8 along i (L1 line reuse
        // within the unrolled burst); g loads + stores coalesced across lanes
        int bc = id - Bdim * Cdim, b = bc >> 7;
        size_t rbase = (size_t)bc * SS + (size_t)j * Sdim + i0;   // + t
        size_t obase = (size_t)bc * SS + j;                       // + (i<<8)
        const float* Gb = Gh + (b << 16) + j;

        float L = 0.f, P = 1.f;
        #pragma unroll
        for (int t8 = 0; t8 < 8; ++t8) {
            ushort8v v8 = *reinterpret_cast<const ushort8v*>(v + rbase + t8 * 8);
            #pragma unroll
            for (int k = 0; k < 8; ++k) {
                float g = Gb[(i0 + t8 * 8 + k) << 8];
                L = fmaf(L, g, bf2f(v8[k]));
                P *= g;
            }
        }
        Ls[q][j] = L; Ps[q][j] = P;
        __syncthreads();
        float C = 0.f;
        for (int r = 0; r < q; ++r) C = Ls[r][j] + C * Ps[r][j];

        float h = C;
        #pragma unroll
        for (int t8 = 0; t8 < 8; ++t8) {
            ushort8v v8 = *reinterpret_cast<const ushort8v*>(v + rbase + t8 * 8);
            ushort8v u8 = *reinterpret_cast<const ushort8v*>(u + rbase + t8 * 8);
            #pragma unroll
            for (int k = 0; k < 8; ++k) {
                int i = i0 + t8 * 8 + k;
                float g = Gb[i << 8];
                h = fmaf(h, g, bf2f(v8[k]));
                oh[obase + ((size_t)i << 8)] = f2bf(h * bf2f(u8[k]));
            }
        }
    }
}

// ---------------- K3: merge via MFMA (verified round 5) ----------------
__global__ __launch_bounds__(256, 2) void k_merge_mfma(
    const unsigned short* __restrict__ ov, const unsigned short* __restrict__ oh,
    const unsigned short* __restrict__ wm_frag,
    const float* __restrict__ b_merge, float* __restrict__ out)
{
    __shared__ unsigned short lds[32768];   // 64 KB
    const int t   = threadIdx.x;
    const int p0  = blockIdx.x * 128;
    const int b   = p0 >> 16;
    const int hw0 = p0 & (SS - 1);

    {
        const int csub = (t >> 4) & 3;
        const int w0   = (t & 15) * 8;
        for (int pass = 0; pass < 64; ++pass) {
            int c = pass * 4 + csub;
            const unsigned short* src = (c < Cdim)
                ? ov + (((size_t)(b * Cdim + c)) << 16) + hw0 + w0
                : oh + (((size_t)(b * Cdim + (c - Cdim))) << 16) + hw0 + w0;
            ushort8v val = *reinterpret_cast<const ushort8v*>(src);
            int off = ((w0 >> 4) << 12) + ((c >> 2) << 6) + ((c & 3) << 4) + (w0 & 15);
            *reinterpret_cast<ushort8v*>(&lds[off]) = val;
        }
    }
    __syncthreads();

    const int lane = t & 63;
    const int wave = t >> 6;
    const unsigned v_addr = lds_addr_of(lds)
        + (unsigned)((wave << 14) + (((t >> 4) & 3) << 7) + ((t & 15) << 3));

    float4v acc[8][2];
    #pragma unroll
    for (int mt = 0; mt < 8; ++mt) {
        acc[mt][0] = (float4v){0.f, 0.f, 0.f, 0.f};
        acc[mt][1] = (float4v){0.f, 0.f, 0.f, 0.f};
    }

    const short8v* wf = reinterpret_cast<const short8v*>(wm_frag);

    for (int ks = 0; ks < 8; ++ks) {
        short8v a[8];
        #pragma unroll
        for (int mt = 0; mt < 8; ++mt) a[mt] = wf[((ks << 3) + mt) * 64 + lane];

        unsigned ka = v_addr + (unsigned)(ks << 10);
        unsigned long long b00, b01, b10, b11;
        asm volatile(
            "ds_read_b64_tr_b16 %0, %4 offset:0\n\t"
            "ds_read_b64_tr_b16 %1, %4 offset:512\n\t"
            "ds_read_b64_tr_b16 %2, %4 offset:8192\n\t"
            "ds_read_b64_tr_b16 %3, %4 offset:8704\n\t"
            "s_waitcnt lgkmcnt(0)"
            : "=&v"(b00), "=&v"(b01), "=&v"(b10), "=&v"(b11)
            : "v"(ka));
        __builtin_amdgcn_sched_barrier(0);

        union { unsigned long long u[2]; short8v v; } f0, f1;
        f0.u[0] = b00; f0.u[1] = b01;
        f1.u[0] = b10; f1.u[1] = b11;
        short8v bn0 = f0.v;
        short8v bn1 = f1.v;

        #pragma unroll
        for (int mt = 0; mt < 8; ++mt) {
            acc[mt][0] = __builtin_amdgcn_mfma_f32_16x16x32_bf16(a[mt], bn0, acc[mt][0], 0, 0, 0);
            acc[mt][1] = __builtin_amdgcn_mfma_f32_16x16x32_bf16(a[mt], bn1, acc[mt][1], 0, 0, 0);
        }
    }

    const int pl = (wave << 5) + (lane & 15);
    const int r0 = (lane >> 4) << 2;
    #pragma unroll
    for (int mt = 0; mt < 8; ++mt) {
        #pragma unroll
        for (int nt = 0; nt < 2; ++nt) {
            size_t col = (size_t)hw0 + pl + nt * 16;
            #pragma unroll
            for (int r = 0; r < 4; ++r) {
                int co = (mt << 4) + r0 + r;
                out[(((size_t)(b * Cdim + co)) << 16) + col] = acc[mt][nt][r] + b_merge[co];
            }
        }
    }
}

extern "C" void kernel_launch(void* const* d_in, const int* in_sizes, int n_in,
                              void* d_out, int out_size, void* d_ws, size_t ws_size,
                              hipStream_t stream)
{
    const float* x        = (const float*)d_in[0];
    const float* w_reduce = (const float*)d_in[1];
    const float* b_red    = (const float*)d_in[2];
    const float* w_u      = (const float*)d_in[3];
    const float* b_u      = (const float*)d_in[4];
    const float* w_lam    = (const float*)d_in[5];
    const float* b_lam    = (const float*)d_in[6];
    const float* w_w      = (const float*)d_in[7];
    const float* b_w      = (const float*)d_in[8];
    const float* w_merge  = (const float*)d_in[11];
    const float* b_merge  = (const float*)d_in[12];
    float* out = (float*)d_out;

    char* ws = (char*)d_ws;
    unsigned short* u_buf = (unsigned short*)(ws);                 // 32 MiB bf16
    unsigned short* v_buf = (unsigned short*)(ws + 33554432);      // 32 MiB  (v = lam*x)
    unsigned short* ov    = (unsigned short*)(ws + 67108864);      // 32 MiB
    unsigned short* oh    = (unsigned short*)(ws + 100663296);     // 32 MiB
    float* Gv    = (float*)(ws + 134217728);                       // 512 KiB
    float* Gh    = (float*)(ws + 134742016);                       // 512 KiB
    unsigned short* wm_frag = (unsigned short*)(ws + 135282688);   // 64 KiB bf16

    unsigned short* wredA = (unsigned short*)(ws + 67108864);          // 12 KiB
    unsigned short* wuA   = (unsigned short*)(ws + 67108864 + 16384);  // 8 KiB
    unsigned short* wlamA = (unsigned short*)(ws + 67108864 + 24576);  // 8 KiB
    float* biasFrag       = (float*)(ws + 67108864 + 32768);           // 3 KiB
    float* buFrag         = (float*)(ws + 67108864 + 36864);           // 8 KiB
    float* blamFrag       = (float*)(ws + 67108864 + 45056);           // 8 KiB

    hipLaunchKernelGGL(k_prep, dim3(64), dim3(256), 0, stream,
                       w_reduce, w_u, w_lam, w_w, b_red, b_u, b_lam, b_w, w_merge,
                       wm_frag, wredA, wuA, wlamA, biasFrag, buFrag, blamFrag);
    hipLaunchKernelGGL(k_front, dim3(NPOS / 128), dim3(256), 0, stream,
                       x, wredA, biasFrag, wuA, wlamA, buFrag, blamFrag,
                       u_buf, v_buf, Gv, Gh);
    hipLaunchKernelGGL(k_scan_chunked, dim3(2 * Bdim * Cdim), dim3(1024), 0, stream,
                       u_buf, v_buf, Gv, Gh, ov, oh);
    hipLaunchKernelGGL(k_merge_mfma, dim3(NPOS / 128), dim3(256), 0, stream,
                       ov, oh, wm_frag, b_merge, out);
}

// Round 8
// 105.386 us; speedup vs baseline: 2.2108x; 2.2108x over previous
//
#include <hip/hip_runtime.h>
#include <hip/hip_bf16.h>

constexpr int Sdim = 256;
constexpr int Cdim = 128;
constexpr int CRdim = 32;
constexpr int Bdim = 2;
constexpr int SS = Sdim * Sdim;      // 65536
constexpr int NPOS = Bdim * SS;      // 131072

typedef __attribute__((ext_vector_type(8))) short short8v;
typedef __attribute__((ext_vector_type(8))) unsigned short ushort8v;
typedef __attribute__((ext_vector_type(4))) float float4v;

__device__ __forceinline__ float bf2f(unsigned short v) {
    union { unsigned u; float f; } t; t.u = ((unsigned)v) << 16; return t.f;
}
__device__ __forceinline__ unsigned short f2bf(float f) {
    unsigned u = __float_as_uint(f);
    return (unsigned short)((u + 0x7fffu + ((u >> 16) & 1u)) >> 16);
}
__device__ __forceinline__ unsigned lds_addr_of(const void* p) {
    return (unsigned)(uintptr_t)(__attribute__((address_space(3))) const void*)p;
}

// ---------------- K0: weight prep ----------------
// All MFMA A-fragments use pi(g,i) = g*4+i (i<4) else 16+g*4+(i-4), matching
// the B-side ds_read_b64_tr_b16 order (verified by round-5 k_merge_mfma).
__global__ void k_prep(const float* __restrict__ w_reduce,
                       const float* __restrict__ w_u, const float* __restrict__ w_lam,
                       const float* __restrict__ w_w,
                       const float* __restrict__ b_red, const float* __restrict__ b_u,
                       const float* __restrict__ b_lam, const float* __restrict__ b_w,
                       const float* __restrict__ w_merge,
                       unsigned short* __restrict__ wm_frag,
                       unsigned short* __restrict__ wredA,
                       unsigned short* __restrict__ wuA, unsigned short* __restrict__ wlamA,
                       float* __restrict__ biasFrag,
                       float* __restrict__ buFrag, float* __restrict__ blamFrag)
{
    int t = blockIdx.x * 256 + threadIdx.x;   // 0..16383
    #pragma unroll
    for (int rep = 0; rep < 2; ++rep) {
        int f = t + rep * 16384;              // 0..32767
        int fi = f & 7, fl = (f >> 3) & 63, mt = (f >> 9) & 7, ks = (f >> 12) & 7;
        int fg = fl >> 4;
        int fk = (fi < 4) ? (fg * 4 + fi) : (16 + fg * 4 + (fi - 4));
        int cc = ks * 32 + fk;
        int co = mt * 16 + (fl & 15);
        float v;
        if (cc < 128) v = w_merge[co * 512 + cc]       + w_merge[co * 512 + cc + 128];
        else          v = w_merge[co * 512 + cc + 128] + w_merge[co * 512 + cc + 256];
        wm_frag[f] = f2bf(v);
    }

    int i = t & 7, lane = (t >> 3) & 63;
    int g = lane >> 4;
    int kk = (i < 4) ? (g * 4 + i) : (16 + g * 4 + (i - 4));

    if (t < 6144) {   // red/pre GEMM A-frags: [ks(4)][mt(3)][lane][i], K=128
        int q = t >> 9, mt = q % 3, ks = q / 3;
        int k = ks * 32 + kk;
        int row = mt * 16 + (lane & 15);
        float v = 0.f;
        if (row < 32) v = w_reduce[row * 128 + k];
        else if (row < 35) {
            int r = row - 32;
            for (int cr = 0; cr < 32; ++cr) v += w_w[r * 32 + cr] * w_reduce[cr * 128 + k];
        }
        wredA[t] = f2bf(v);
    }
    if (t < 4096) {   // u/lam GEMM A-frags: [mt(8)][lane][i], K=32 (kk = cr)
        int mt = t >> 9;
        int co = mt * 16 + (lane & 15);
        wuA[t]   = f2bf(w_u[co * 32 + kk]);
        wlamA[t] = f2bf(w_lam[co * 32 + kk]);
    }
    if (t < 768) {    // bias in D-frag layout for red/pre rows
        int r = t & 3, ln = (t >> 2) & 63, mt = t >> 8;
        int row = mt * 16 + (ln >> 4) * 4 + r;
        float v = 0.f;
        if (row < 32) v = b_red[row];
        else if (row < 35) {
            int rr = row - 32;
            v = b_w[rr];
            for (int cr = 0; cr < 32; ++cr) v += w_w[rr * 32 + cr] * b_red[cr];
        }
        biasFrag[t] = v;
    }
    if (t < 2048) {   // u/lam bias in D-frag layout
        int r = t & 3, ln = (t >> 2) & 63, mt = t >> 8;
        int co = mt * 16 + (ln >> 4) * 4 + r;
        buFrag[t]   = b_u[co];
        blamFrag[t] = b_lam[co];
    }
}

// ---------------- K1: fused front end via MFMA (verified round 6) ----------------
__global__ __launch_bounds__(256, 4) void k_front(
    const float* __restrict__ x,
    const unsigned short* __restrict__ wredA, const float* __restrict__ biasFrag,
    const unsigned short* __restrict__ wuA, const unsigned short* __restrict__ wlamA,
    const float* __restrict__ buFrag, const float* __restrict__ blamFrag,
    unsigned short* __restrict__ u_o, unsigned short* __restrict__ v_o,
    float* __restrict__ Gv, float* __restrict__ Gh)
{
    __shared__ unsigned short lds[20480];   // 32KB X-tile + 8KB red-tile
    const int t   = threadIdx.x;
    const int p0  = blockIdx.x * 128;
    const int b   = p0 >> 16;
    const int hw0 = p0 & (SS - 1);

    {
        const int w0 = (t & 15) * 8;
        #pragma unroll
        for (int pass = 0; pass < 8; ++pass) {
            int c = (t >> 4) + pass * 16;
            const float* src = x + (((size_t)(b * Cdim + c)) << 16) + hw0 + w0;
            float4 xa = *reinterpret_cast<const float4*>(src);
            float4 xb = *reinterpret_cast<const float4*>(src + 4);
            ushort8v val;
            val[0] = f2bf(xa.x); val[1] = f2bf(xa.y); val[2] = f2bf(xa.z); val[3] = f2bf(xa.w);
            val[4] = f2bf(xb.x); val[5] = f2bf(xb.y); val[6] = f2bf(xb.z); val[7] = f2bf(xb.w);
            int off = ((w0 >> 4) << 11) + ((c >> 2) << 6) + ((c & 3) << 4) + (w0 & 15);
            *reinterpret_cast<ushort8v*>(&lds[off]) = val;
        }
    }
    __syncthreads();

    const int lane = t & 63;
    const int wave = t >> 6;
    const int g    = lane >> 4;

    const unsigned vx = lds_addr_of(lds)
        + (unsigned)((wave << 13) + (g << 7) + ((lane & 15) << 3));

    float4v redD[3][2];
    #pragma unroll
    for (int mt = 0; mt < 3; ++mt) {
        redD[mt][0] = (float4v){0.f, 0.f, 0.f, 0.f};
        redD[mt][1] = (float4v){0.f, 0.f, 0.f, 0.f};
    }
    const short8v* wfr = reinterpret_cast<const short8v*>(wredA);
    #pragma unroll
    for (int ks = 0; ks < 4; ++ks) {
        short8v a0 = wfr[(ks * 3 + 0) * 64 + lane];
        short8v a1 = wfr[(ks * 3 + 1) * 64 + lane];
        short8v a2 = wfr[(ks * 3 + 2) * 64 + lane];
        unsigned ka = vx + (unsigned)(ks << 10);
        unsigned long long q00, q01, q10, q11;
        asm volatile(
            "ds_read_b64_tr_b16 %0, %4 offset:0\n\t"
            "ds_read_b64_tr_b16 %1, %4 offset:512\n\t"
            "ds_read_b64_tr_b16 %2, %4 offset:4096\n\t"
            "ds_read_b64_tr_b16 %3, %4 offset:4608\n\t"
            "s_waitcnt lgkmcnt(0)"
            : "=&v"(q00), "=&v"(q01), "=&v"(q10), "=&v"(q11)
            : "v"(ka));
        __builtin_amdgcn_sched_barrier(0);
        union { unsigned long long u[2]; short8v v; } f0, f1;
        f0.u[0] = q00; f0.u[1] = q01;
        f1.u[0] = q10; f1.u[1] = q11;
        short8v bn0 = f0.v, bn1 = f1.v;
        redD[0][0] = __builtin_amdgcn_mfma_f32_16x16x32_bf16(a0, bn0, redD[0][0], 0, 0, 0);
        redD[0][1] = __builtin_amdgcn_mfma_f32_16x16x32_bf16(a0, bn1, redD[0][1], 0, 0, 0);
        redD[1][0] = __builtin_amdgcn_mfma_f32_16x16x32_bf16(a1, bn0, redD[1][0], 0, 0, 0);
        redD[1][1] = __builtin_amdgcn_mfma_f32_16x16x32_bf16(a1, bn1, redD[1][1], 0, 0, 0);
        redD[2][0] = __builtin_amdgcn_mfma_f32_16x16x32_bf16(a2, bn0, redD[2][0], 0, 0, 0);
        redD[2][1] = __builtin_amdgcn_mfma_f32_16x16x32_bf16(a2, bn1, redD[2][1], 0, 0, 0);
    }

    {
        float4 bp = *reinterpret_cast<const float4*>(biasFrag + ((2 * 64 + lane) << 2));
        if (lane < 16) {
            #pragma unroll
            for (int nt = 0; nt < 2; ++nt) {
                float pr0 = redD[2][nt][0] + bp.x;
                float pr1 = redD[2][nt][1] + bp.y;
                float pr2 = redD[2][nt][2] + bp.z;
                float s0 = 1.f / (1.f + expf(-pr0));
                float s1 = 1.f / (1.f + expf(-pr1));
                float s2 = 1.f / (1.f + expf(-pr2));
                float inv = 1.f / fmaxf(s0 + s1 + s2, 1e-6f);
                int hw = hw0 + wave * 32 + nt * 16 + lane;
                int hh = hw >> 8, wp = hw & 255;
                float ghv = (s1 + (hh >= 1 ? s0 : 0.f) + (hh <= Sdim - 2 ? s2 : 0.f)) * inv;
                float gvv = (s1 + (wp >= 1 ? s0 : 0.f) + (wp <= Sdim - 2 ? s2 : 0.f)) * inv;
                Gh[(b << 16) + hw] = ghv;
                Gv[(b << 16) + (wp << 8) + hh] = gvv;
            }
        }
    }

    #pragma unroll
    for (int mt = 0; mt < 2; ++mt) {
        float4 bb = *reinterpret_cast<const float4*>(biasFrag + ((mt * 64 + lane) << 2));
        #pragma unroll
        for (int nt = 0; nt < 2; ++nt) {
            int pp = wave * 32 + nt * 16 + (lane & 15);
            #pragma unroll
            for (int r = 0; r < 4; ++r) {
                int cr = mt * 16 + g * 4 + r;
                float bval = (r == 0 ? bb.x : r == 1 ? bb.y : r == 2 ? bb.z : bb.w);
                int off = 16384 + ((pp >> 4) << 9) + ((cr >> 2) << 6) + ((cr & 3) << 4) + (pp & 15);
                lds[off] = f2bf(redD[mt][nt][r] + bval);
            }
        }
    }
    __syncthreads();

    const unsigned vr = lds_addr_of(lds) + 32768u
        + (unsigned)((wave << 11) + (g << 7) + ((lane & 15) << 3));
    unsigned long long q00, q01, q10, q11;
    asm volatile(
        "ds_read_b64_tr_b16 %0, %4 offset:0\n\t"
        "ds_read_b64_tr_b16 %1, %4 offset:512\n\t"
        "ds_read_b64_tr_b16 %2, %4 offset:1024\n\t"
        "ds_read_b64_tr_b16 %3, %4 offset:1536\n\t"
        "s_waitcnt lgkmcnt(0)"
        : "=&v"(q00), "=&v"(q01), "=&v"(q10), "=&v"(q11)
        : "v"(vr));
    __builtin_amdgcn_sched_barrier(0);
    union { unsigned long long u[2]; short8v v; } fb0, fb1;
    fb0.u[0] = q00; fb0.u[1] = q01;
    fb1.u[0] = q10; fb1.u[1] = q11;
    short8v bn0 = fb0.v, bn1 = fb1.v;

    const short8v* wfu = reinterpret_cast<const short8v*>(wuA);
    const short8v* wfl = reinterpret_cast<const short8v*>(wlamA);
    const float4v zz = (float4v){0.f, 0.f, 0.f, 0.f};
    #pragma unroll
    for (int mt = 0; mt < 8; ++mt) {
        short8v au = wfu[(mt << 6) + lane];
        short8v al = wfl[(mt << 6) + lane];
        float4v u0 = __builtin_amdgcn_mfma_f32_16x16x32_bf16(au, bn0, zz, 0, 0, 0);
        float4v u1 = __builtin_amdgcn_mfma_f32_16x16x32_bf16(au, bn1, zz, 0, 0, 0);
        float4v l0 = __builtin_amdgcn_mfma_f32_16x16x32_bf16(al, bn0, zz, 0, 0, 0);
        float4v l1 = __builtin_amdgcn_mfma_f32_16x16x32_bf16(al, bn1, zz, 0, 0, 0);
        float4 bu = *reinterpret_cast<const float4*>(buFrag + ((mt * 64 + lane) << 2));
        float4 bl = *reinterpret_cast<const float4*>(blamFrag + ((mt * 64 + lane) << 2));
        #pragma unroll
        for (int nt = 0; nt < 2; ++nt) {
            float4v uu = nt ? u1 : u0;
            float4v ll = nt ? l1 : l0;
            int pp = wave * 32 + nt * 16 + (lane & 15);
            #pragma unroll
            for (int r = 0; r < 4; ++r) {
                int co = mt * 16 + g * 4 + r;
                int xoff = ((pp >> 4) << 11) + ((co >> 2) << 6) + ((co & 3) << 4) + (pp & 15);
                float xv = bf2f(lds[xoff]);
                float bur = (r == 0 ? bu.x : r == 1 ? bu.y : r == 2 ? bu.z : bu.w);
                float blr = (r == 0 ? bl.x : r == 1 ? bl.y : r == 2 ? bl.z : bl.w);
                size_t gidx = (((size_t)(b * Cdim + co)) << 16) + (size_t)(hw0 + pp);
                u_o[gidx] = f2bf(uu[r] + bur);
                v_o[gidx] = f2bf((ll[r] + blr) * xv);
            }
        }
    }
}

// ---------------- K2: 2-chunk scan with exact carry ----------------
// Block = 512 threads = (half = tid>>8, column j = tid&255), one (dir,b,c)
// plane per block. Half 0: true scan over i in [0,128), writes output, posts
// h127 to LDS. Half 1 (concurrent): (L,P) over [128,256) -- same cold-stream
// cost, parallel; after barrier, rescans its half (v now L2-warm, 64KB/block)
// emitting (L + h127*P)*u. Critical path 128 cold + 128 warm vs 256 cold;
// waves 2x round-6. Interior gains are exactly 1.0 (full masks => normalized
// sum = 1), so P never underflows and the split is numerically benign.
// Round-7 lesson baked in: no extra cold streams, concurrent footprint
// matches round-6 (halves of the same plane).
__global__ __launch_bounds__(512, 4) void k_scan_split(
    const unsigned short* __restrict__ u, const unsigned short* __restrict__ v,
    const float* __restrict__ Gv, const float* __restrict__ Gh,
    unsigned short* __restrict__ ov, unsigned short* __restrict__ oh)
{
    __shared__ float Hb[256];

    const int id   = blockIdx.x;
    const int j    = threadIdx.x & 255;
    const int half = threadIdx.x >> 8;    // wave-uniform
    const bool vert = (id < Bdim * Cdim);

    float L = 0.f, P = 1.f;               // half-1 carry pieces

    if (vert) {
        int bc = id, b = bc >> 7;
        size_t base = (size_t)bc * SS + j;
        const float* Gb = Gv + (b << 16) + j;
        if (half == 0) {
            float h = 0.f;
            #pragma unroll 8
            for (int i = 0; i < 128; ++i) {
                size_t idx = base + ((size_t)i << 8);
                float g = Gb[i << 8];
                h = fmaf(h, g, bf2f(v[idx]));
                ov[idx] = f2bf(h * bf2f(u[idx]));
            }
            Hb[j] = h;
        } else {
            #pragma unroll 8
            for (int i = 128; i < 256; ++i) {
                float g = Gb[i << 8];
                L = fmaf(L, g, bf2f(v[base + ((size_t)i << 8)]));
                P *= g;
            }
        }
    } else {
        int bc = id - Bdim * Cdim, b = bc >> 7;
        size_t rbase = (size_t)bc * SS + (size_t)j * Sdim;
        const float* Gb = Gh + (b << 16) + j;
        if (half == 0) {
            size_t obase = (size_t)bc * SS + j;
            float h = 0.f;
            #pragma unroll
            for (int t8 = 0; t8 < 16; ++t8) {
                ushort8v v8 = *reinterpret_cast<const ushort8v*>(v + rbase + t8 * 8);
                ushort8v u8 = *reinterpret_cast<const ushort8v*>(u + rbase + t8 * 8);
                #pragma unroll
                for (int k = 0; k < 8; ++k) {
                    int i = t8 * 8 + k;
                    float g = Gb[i << 8];
                    h = fmaf(h, g, bf2f(v8[k]));
                    oh[obase + ((size_t)i << 8)] = f2bf(h * bf2f(u8[k]));
                }
            }
            Hb[j] = h;
        } else {
            #pragma unroll
            for (int t8 = 0; t8 < 16; ++t8) {
                ushort8v v8 = *reinterpret_cast<const ushort8v*>(v + rbase + 128 + t8 * 8);
                #pragma unroll
                for (int k = 0; k < 8; ++k) {
                    float g = Gb[(128 + t8 * 8 + k) << 8];
                    L = fmaf(L, g, bf2f(v8[k]));
                    P *= g;
                }
            }
        }
    }

    __syncthreads();

    if (half == 1) {
        float h0;
        if (vert) {
            int bc = id;
            size_t base = (size_t)bc * SS + j;
            const float* Gb = Gv + ((bc >> 7) << 16) + j;
            h0 = Hb[j];
            float Lr = 0.f, Pr = 1.f;
            #pragma unroll 8
            for (int i = 128; i < 256; ++i) {
                size_t idx = base + ((size_t)i << 8);
                float g = Gb[i << 8];
                Lr = fmaf(Lr, g, bf2f(v[idx]));     // L2-warm reread
                Pr *= g;
                float h = fmaf(h0, Pr, Lr);
                ov[idx] = f2bf(h * bf2f(u[idx]));
            }
        } else {
            int bc = id - Bdim * Cdim;
            size_t rbase = (size_t)bc * SS + (size_t)j * Sdim;
            size_t obase = (size_t)bc * SS + j;
            const float* Gb = Gh + ((bc >> 7) << 16) + j;
            h0 = Hb[j];
            float Lr = 0.f, Pr = 1.f;
            #pragma unroll
            for (int t8 = 0; t8 < 16; ++t8) {
                ushort8v v8 = *reinterpret_cast<const ushort8v*>(v + rbase + 128 + t8 * 8);
                ushort8v u8 = *reinterpret_cast<const ushort8v*>(u + rbase + 128 + t8 * 8);
                #pragma unroll
                for (int k = 0; k < 8; ++k) {
                    int i = 128 + t8 * 8 + k;
                    float g = Gb[i << 8];
                    Lr = fmaf(Lr, g, bf2f(v8[k]));
                    Pr *= g;
                    float h = fmaf(h0, Pr, Lr);
                    oh[obase + ((size_t)i << 8)] = f2bf(h * bf2f(u8[k]));
                }
            }
        }
        (void)h0; (void)L; (void)P;
    }
}

// ---------------- K3: merge via MFMA (verified round 5) ----------------
__global__ __launch_bounds__(256, 2) void k_merge_mfma(
    const unsigned short* __restrict__ ov, const unsigned short* __restrict__ oh,
    const unsigned short* __restrict__ wm_frag,
    const float* __restrict__ b_merge, float* __restrict__ out)
{
    __shared__ unsigned short lds[32768];   // 64 KB
    const int t   = threadIdx.x;
    const int p0  = blockIdx.x * 128;
    const int b   = p0 >> 16;
    const int hw0 = p0 & (SS - 1);

    {
        const int csub = (t >> 4) & 3;
        const int w0   = (t & 15) * 8;
        for (int pass = 0; pass < 64; ++pass) {
            int c = pass * 4 + csub;
            const unsigned short* src = (c < Cdim)
                ? ov + (((size_t)(b * Cdim + c)) << 16) + hw0 + w0
                : oh + (((size_t)(b * Cdim + (c - Cdim))) << 16) + hw0 + w0;
            ushort8v val = *reinterpret_cast<const ushort8v*>(src);
            int off = ((w0 >> 4) << 12) + ((c >> 2) << 6) + ((c & 3) << 4) + (w0 & 15);
            *reinterpret_cast<ushort8v*>(&lds[off]) = val;
        }
    }
    __syncthreads();

    const int lane = t & 63;
    const int wave = t >> 6;
    const unsigned v_addr = lds_addr_of(lds)
        + (unsigned)((wave << 14) + (((t >> 4) & 3) << 7) + ((t & 15) << 3));

    float4v acc[8][2];
    #pragma unroll
    for (int mt = 0; mt < 8; ++mt) {
        acc[mt][0] = (float4v){0.f, 0.f, 0.f, 0.f};
        acc[mt][1] = (float4v){0.f, 0.f, 0.f, 0.f};
    }

    const short8v* wf = reinterpret_cast<const short8v*>(wm_frag);

    for (int ks = 0; ks < 8; ++ks) {
        short8v a[8];
        #pragma unroll
        for (int mt = 0; mt < 8; ++mt) a[mt] = wf[((ks << 3) + mt) * 64 + lane];

        unsigned ka = v_addr + (unsigned)(ks << 10);
        unsigned long long b00, b01, b10, b11;
        asm volatile(
            "ds_read_b64_tr_b16 %0, %4 offset:0\n\t"
            "ds_read_b64_tr_b16 %1, %4 offset:512\n\t"
            "ds_read_b64_tr_b16 %2, %4 offset:8192\n\t"
            "ds_read_b64_tr_b16 %3, %4 offset:8704\n\t"
            "s_waitcnt lgkmcnt(0)"
            : "=&v"(b00), "=&v"(b01), "=&v"(b10), "=&v"(b11)
            : "v"(ka));
        __builtin_amdgcn_sched_barrier(0);

        union { unsigned long long u[2]; short8v v; } f0, f1;
        f0.u[0] = b00; f0.u[1] = b01;
        f1.u[0] = b10; f1.u[1] = b11;
        short8v bn0 = f0.v;
        short8v bn1 = f1.v;

        #pragma unroll
        for (int mt = 0; mt < 8; ++mt) {
            acc[mt][0] = __builtin_amdgcn_mfma_f32_16x16x32_bf16(a[mt], bn0, acc[mt][0], 0, 0, 0);
            acc[mt][1] = __builtin_amdgcn_mfma_f32_16x16x32_bf16(a[mt], bn1, acc[mt][1], 0, 0, 0);
        }
    }

    const int pl = (wave << 5) + (lane & 15);
    const int r0 = (lane >> 4) << 2;
    #pragma unroll
    for (int mt = 0; mt < 8; ++mt) {
        #pragma unroll
        for (int nt = 0; nt < 2; ++nt) {
            size_t col = (size_t)hw0 + pl + nt * 16;
            #pragma unroll
            for (int r = 0; r < 4; ++r) {
                int co = (mt << 4) + r0 + r;
                out[(((size_t)(b * Cdim + co)) << 16) + col] = acc[mt][nt][r] + b_merge[co];
            }
        }
    }
}

extern "C" void kernel_launch(void* const* d_in, const int* in_sizes, int n_in,
                              void* d_out, int out_size, void* d_ws, size_t ws_size,
                              hipStream_t stream)
{
    const float* x        = (const float*)d_in[0];
    const float* w_reduce = (const float*)d_in[1];
    const float* b_red    = (const float*)d_in[2];
    const float* w_u      = (const float*)d_in[3];
    const float* b_u      = (const float*)d_in[4];
    const float* w_lam    = (const float*)d_in[5];
    const float* b_lam    = (const float*)d_in[6];
    const float* w_w      = (const float*)d_in[7];
    const float* b_w      = (const float*)d_in[8];
    const float* w_merge  = (const float*)d_in[11];
    const float* b_merge  = (const float*)d_in[12];
    float* out = (float*)d_out;

    char* ws = (char*)d_ws;
    unsigned short* u_buf = (unsigned short*)(ws);                 // 32 MiB bf16
    unsigned short* v_buf = (unsigned short*)(ws + 33554432);      // 32 MiB  (v = lam*x)
    unsigned short* ov    = (unsigned short*)(ws + 67108864);      // 32 MiB
    unsigned short* oh    = (unsigned short*)(ws + 100663296);     // 32 MiB
    float* Gv    = (float*)(ws + 134217728);                       // 512 KiB
    float* Gh    = (float*)(ws + 134742016);                       // 512 KiB
    unsigned short* wm_frag = (unsigned short*)(ws + 135282688);   // 64 KiB bf16

    unsigned short* wredA = (unsigned short*)(ws + 67108864);          // 12 KiB
    unsigned short* wuA   = (unsigned short*)(ws + 67108864 + 16384);  // 8 KiB
    unsigned short* wlamA = (unsigned short*)(ws + 67108864 + 24576);  // 8 KiB
    float* biasFrag       = (float*)(ws + 67108864 + 32768);           // 3 KiB
    float* buFrag         = (float*)(ws + 67108864 + 36864);           // 8 KiB
    float* blamFrag       = (float*)(ws + 67108864 + 45056);           // 8 KiB

    hipLaunchKernelGGL(k_prep, dim3(64), dim3(256), 0, stream,
                       w_reduce, w_u, w_lam, w_w, b_red, b_u, b_lam, b_w, w_merge,
                       wm_frag, wredA, wuA, wlamA, biasFrag, buFrag, blamFrag);
    hipLaunchKernelGGL(k_front, dim3(NPOS / 128), dim3(256), 0, stream,
                       x, wredA, biasFrag, wuA, wlamA, buFrag, blamFrag,
                       u_buf, v_buf, Gv, Gh);
    hipLaunchKernelGGL(k_scan_split, dim3(2 * Bdim * Cdim), dim3(512), 0, stream,
                       u_buf, v_buf, Gv, Gh, ov, oh);
    hipLaunchKernelGGL(k_merge_mfma, dim3(NPOS / 128), dim3(256), 0, stream,
                       ov, oh, wm_frag, b_merge, out);
}